// Round 1
// baseline (268.543 us; speedup 1.0000x reference)
//
#include <hip/hip_runtime.h>

#define N_NODES 100000
#define N_EDGES 1600000
#define D 32

// Kernel 1: y = x @ W^T   (y[i,o] = sum_k x[i,k] * W[o,k])
// Block = 256 threads = 8 rows x 32 output cols.
__global__ __launch_bounds__(256) void gcn_linear_kernel(
    const float* __restrict__ x,
    const float* __restrict__ W,
    float* __restrict__ y) {
    // Wt[k*32+o] = W[o*32+k]; reads Wt[k*32+o] with o = lane -> conflict-free.
    __shared__ float Wt[D * D];
    int t = threadIdx.x;
    for (int i = t; i < D * D; i += 256) {
        int o = i >> 5, k = i & 31;
        Wt[k * D + o] = W[i];
    }
    __syncthreads();

    int gid = blockIdx.x * 256 + t;
    int row = gid >> 5;
    int o = gid & 31;
    if (row >= N_NODES) return;

    const float* xr = x + row * D;
    float acc = 0.f;
#pragma unroll
    for (int k = 0; k < D; ++k) {
        acc += xr[k] * Wt[k * D + o];  // xr[k]: broadcast across the 32 lanes of a row
    }
    y[row * D + o] = acc;
}

// Kernel 2: out[dst[e], :] += y[src[e], :]  via atomics.
// Thread = (edge, feature): lane group of 32 handles one edge's row ->
// coalesced 128B gather of y and a contiguous 128B atomic burst.
__global__ __launch_bounds__(256) void gcn_scatter_kernel(
    const int* __restrict__ src,
    const int* __restrict__ dst,
    const float* __restrict__ y,
    float* __restrict__ out) {
    int gid = blockIdx.x * 256 + threadIdx.x;
    int e = gid >> 5;
    int d = gid & 31;
    if (e >= N_EDGES) return;
    int s = src[e];
    int dd = dst[e];
    atomicAdd(&out[dd * D + d], y[s * D + d]);
}

extern "C" void kernel_launch(void* const* d_in, const int* in_sizes, int n_in,
                              void* d_out, int out_size, void* d_ws, size_t ws_size,
                              hipStream_t stream) {
    const float* x = (const float*)d_in[0];
    const int* edge_index = (const int*)d_in[1];  // [2, N_EDGES], int32
    const float* W = (const float*)d_in[2];
    float* out = (float*)d_out;
    float* y = (float*)d_ws;  // N_NODES * D floats = 12.8 MB

    const int* src = edge_index;
    const int* dst = edge_index + N_EDGES;

    // d_out is re-poisoned to 0xAA before every timed launch -> zero it.
    hipMemsetAsync(d_out, 0, (size_t)out_size * sizeof(float), stream);

    // y = x @ W^T
    int lin_threads = N_NODES * D;
    int lin_blocks = (lin_threads + 255) / 256;
    gcn_linear_kernel<<<lin_blocks, 256, 0, stream>>>(x, W, y);

    // out[dst] += y[src]
    int sc_threads = N_EDGES * D;
    int sc_blocks = (sc_threads + 255) / 256;
    gcn_scatter_kernel<<<sc_blocks, 256, 0, stream>>>(src, dst, y, out);
}